// Round 15
// baseline (361.958 us; speedup 1.0000x reference)
//
#include <hip/hip_runtime.h>
#include <hip/hip_bf16.h>
#include <hip/hip_fp16.h>

// GraphConv: out = relu(A_hat @ (X @ W) + b)
// N=100000, E=3200000, F=C=256, fp32 in/out.
//
// Round 13 = round 12 with CH_A3 reverted 32768 -> 8192 (the single cause of
// round 12's regression: 98 bin blocks left ~5% of the machine busy in the
// dispatch tail -> kD1 233us. 391 bin blocks ~ one gemm block's duration each
// -> flush finish, kD1 ~115us as in round 11).
//  * Kept from round 12: packed int2 {cv,lr} binning (one 8B scattered store
//    per edge), kB2 single-stage sort with in-place sorted-cv writeback,
//    rowinfo {start,cnt}.
//  * Agg pinned (rounds 5-8: L2-miss-fill bound, 750MB @ ~3.8TB/s; MLP/width/
//    blocking insensitive). fp8-H rejected: predicted max err ~0.5-0.7 vs
//    threshold 0.4175.
//
// Pipeline: k_pre -> kD1 (bin || gemm) -> kB2 (sort) -> k_agg.

#define CAP 2432
#define NBMAX 1600
#define CH_A3 8192
#define D1_SMEM 19200

typedef __attribute__((ext_vector_type(4))) float f32x4;
typedef __attribute__((ext_vector_type(8))) short s16x8;

__device__ __forceinline__ unsigned short f2bf(float f) {
    unsigned u = __float_as_uint(f);
    u += 0x7FFFu + ((u >> 16) & 1u);   // RNE
    return (unsigned short)(u >> 16);
}
__device__ __forceinline__ float bf2f(unsigned short s) {
    return __uint_as_float(((unsigned)s) << 16);
}

// ---------------- k_pre: Wt[c][k] = bf16(W[k][c]); zero gcur ----------------
__global__ __launch_bounds__(256) void k_pre(const float* __restrict__ W,
                                             unsigned short* __restrict__ Wt,
                                             int* __restrict__ gcur, int NB) {
    int bid = blockIdx.x, t = threadIdx.x;
    if (bid < 256) {
        int idx = bid * 256 + t;        // 65536 elems
        int k = idx >> 8, c = idx & 255;
        Wt[c * 256 + k] = f2bf(W[idx]);
    } else {
        for (int j = t; j < NB; j += 256) gcur[j] = 0;
    }
}

// ---------------- A3: bin edges into fixed-capacity buckets -----------------
// One packed int2 {cv, lr} scattered write per edge.
__device__ __forceinline__ void a3_body(const int* __restrict__ row,
                                        const int* __restrict__ col,
                                        const float* __restrict__ val,
                                        int* __restrict__ gcur,
                                        int2* __restrict__ bin8,
                                        int E, int NB, int chunk, char* smem) {
    int* h    = (int*)smem;         // NB
    int* base = h + NBMAX;          // NB
    int* cur  = base + NBMAX;       // NB
    int t = threadIdx.x;
    for (int j = t; j < NB; j += 256) { h[j] = 0; cur[j] = 0; }
    __syncthreads();
    int start = chunk * CH_A3;
    int end = min(E, start + CH_A3);
    for (int i = start + t; i < end; i += 256)
        atomicAdd(&h[row[i] >> 6], 1);
    __syncthreads();
    for (int j = t; j < NB; j += 256) {
        int c = h[j];
        base[j] = c ? atomicAdd(&gcur[j], c) : 0;
    }
    __syncthreads();
    for (int i = start + t; i < end; i += 256) {
        int r = row[i];
        int b = r >> 6;
        int ofs = atomicAdd(&cur[b], 1);
        unsigned hb = (unsigned)__half_as_ushort(__float2half(val[i]));  // sign=0
        bin8[(size_t)b * CAP + base[b] + ofs] =
            make_int2((int)((unsigned)col[i] | (hb << 17)), r & 63);
    }
}

// ---------------- MFMA GEMM tile body (round-9, verified) -------------------
// Block g: rows [g*64, g*64+64) x all 256 cols. 4 waves: wave w owns cols
// [w*64, w*64+64) -> acc[4][4] frags of 16x16x32, fp32 accum. X cast to bf16
// in-register during LDS staging, read once (NT). B frags from Wt (L2-hot).
__device__ __forceinline__ void gemm_body(const float* __restrict__ X,
                                          const unsigned short* __restrict__ Wt,
                                          unsigned short* __restrict__ H,
                                          int M, int g, char* smem) {
    typedef unsigned short AsRow[40];
    AsRow* As = (AsRow*)smem;
    int t = threadIdx.x;
    int lane = t & 63;
    int w = t >> 6;
    int r0 = g * 64;
    int c0 = w * 64;
    int srow = t >> 2;
    int sslot = t & 3;
    int gr = r0 + srow; if (gr >= M) gr = M - 1;

    f32x4 acc[4][4] = {};

    for (int k0 = 0; k0 < 256; k0 += 32) {
        const float* p = &X[(size_t)gr * 256 + k0 + sslot * 8];
        f32x4 a0 = __builtin_nontemporal_load((const f32x4*)p);
        f32x4 a1 = __builtin_nontemporal_load((const f32x4*)(p + 4));
        s16x8 va;
        va[0] = (short)f2bf(a0[0]); va[1] = (short)f2bf(a0[1]);
        va[2] = (short)f2bf(a0[2]); va[3] = (short)f2bf(a0[3]);
        va[4] = (short)f2bf(a1[0]); va[5] = (short)f2bf(a1[1]);
        va[6] = (short)f2bf(a1[2]); va[7] = (short)f2bf(a1[3]);
        __syncthreads();
        *(s16x8*)&As[srow][sslot * 8] = va;
        __syncthreads();

        int kofs = (lane >> 4) * 8;
        s16x8 afr[4], bfr[4];
#pragma unroll
        for (int mi = 0; mi < 4; ++mi)
            afr[mi] = *(const s16x8*)&As[mi * 16 + (lane & 15)][kofs];
#pragma unroll
        for (int ni = 0; ni < 4; ++ni) {
            int cn = c0 + ni * 16 + (lane & 15);
            bfr[ni] = *(const s16x8*)&Wt[(size_t)cn * 256 + k0 + kofs];
        }
#pragma unroll
        for (int mi = 0; mi < 4; ++mi)
#pragma unroll
            for (int ni = 0; ni < 4; ++ni)
                acc[mi][ni] = __builtin_amdgcn_mfma_f32_16x16x32_bf16(
                    afr[mi], bfr[ni], acc[mi][ni], 0, 0, 0);
    }

    // C write: col = lane&15, row = (lane>>4)*4 + j  [m89-verified layout]
#pragma unroll
    for (int mi = 0; mi < 4; ++mi) {
#pragma unroll
        for (int ni = 0; ni < 4; ++ni) {
            int rg = r0 + mi * 16 + (lane >> 4) * 4;
            int cg = c0 + ni * 16 + (lane & 15);
#pragma unroll
            for (int j = 0; j < 4; ++j) {
                if (rg + j < M)
                    H[(size_t)(rg + j) * 256 + cg] = f2bf(acc[mi][ni][j]);
            }
        }
    }
}

// ---------------- D1: binning || GEMM ---------------------------------------
__global__ __launch_bounds__(256) void kD1(const int* __restrict__ row,
                                           const int* __restrict__ col,
                                           const float* __restrict__ val,
                                           int* __restrict__ gcur,
                                           int2* __restrict__ bin8,
                                           int E, int NB, int nA3,
                                           const float* __restrict__ X,
                                           const unsigned short* __restrict__ Wt,
                                           unsigned short* __restrict__ H, int M) {
    extern __shared__ char smem[];
    int bid = blockIdx.x;
    if (bid < nA3) {
        a3_body(row, col, val, gcur, bin8, E, NB, bid, smem);
        return;
    }
    gemm_body(X, Wt, H, M, bid - nA3, smem);
}

// ---------------- kB2: per-bucket counting sort ------------------------------
// Block b: stage its <=CAP int2 edges into LDS (single global read), per-wave
// privatized histogram, 64-bin scan, write sorted cv (4B) back into the FIRST
// HALF of its own bucket window (full stage before scatter -> safe).
// rowinfo[node] = {global uint index of row start, count}.
__global__ __launch_bounds__(256) void kB2(int2* __restrict__ bin8,
                                           const int* __restrict__ gcur,
                                           int2* __restrict__ rowinfo, int N) {
    __shared__ int2 se[CAP];
    __shared__ int hist[4][64];
    __shared__ int rs[64], cnt[64];
    int b = blockIdx.x;
    int t = threadIdx.x;
    int w = t >> 6;
    size_t gb = (size_t)b * CAP;
    int n = gcur[b];

    if (t < 64) { hist[0][t] = 0; hist[1][t] = 0; hist[2][t] = 0; hist[3][t] = 0; }
    __syncthreads();
    for (int i = t; i < n; i += 256) {
        int2 e = bin8[gb + i];
        se[i] = e;
        atomicAdd(&hist[w][e.y], 1);
    }
    __syncthreads();
    if (t < 64) {
        int h0 = hist[0][t], h1 = hist[1][t], h2 = hist[2][t], h3 = hist[3][t];
        cnt[t] = h0 + h1 + h2 + h3;
        rs[t] = cnt[t];
        hist[0][t] = 0;
        hist[1][t] = h0;
        hist[2][t] = h0 + h1;
        hist[3][t] = h0 + h1 + h2;
    }
    __syncthreads();
    for (int off = 1; off < 64; off <<= 1) {
        int v = (t < 64 && t >= off) ? rs[t - off] : 0;
        __syncthreads();
        if (t < 64 && t >= off) rs[t] += v;
        __syncthreads();
    }
    unsigned* cvout = (unsigned*)&bin8[gb];      // own window, first half
    if (t < 64) {
        int st = rs[t] - cnt[t];
        hist[0][t] += st; hist[1][t] += st;
        hist[2][t] += st; hist[3][t] += st;
        int node = b * 64 + t;
        if (node < N) rowinfo[node] = make_int2((int)(gb * 2 + st), cnt[t]);
    }
    __syncthreads();
    for (int i = t; i < n; i += 256) {
        int2 e = se[i];
        int pos = atomicAdd(&hist[w][e.y], 1);
        cvout[pos] = (unsigned)e.x;
    }
}

// ---------------- aggregation (round-5 pinned form) --------------------------
// Wave per node. lane = 8 channels (16B gathers); lane-half h processes edge
// i+h -> 2 edges per load instr, 8 edges in flight. Cross-half combine via
// shfl_xor(32). Fused bias + relu. Plain store.
__global__ __launch_bounds__(256) void k_agg(const unsigned short* __restrict__ H,
                                             const int2* __restrict__ rowinfo,
                                             const unsigned* __restrict__ csr,
                                             const float* __restrict__ bias,
                                             float* __restrict__ out, int n) {
    int wave = threadIdx.x >> 6;
    int lane = threadIdx.x & 63;
    int node = blockIdx.x * 4 + wave;
    if (node >= n) return;
    int2 ri = rowinfo[node];
    int s = ri.x;
    int e = ri.x + ri.y;
    int h = lane >> 5;
    int cbase = (lane & 31) * 8;

    float a0=0.f,a1=0.f,a2=0.f,a3=0.f,a4=0.f,a5=0.f,a6=0.f,a7=0.f;

#define ACC(K, HV)                                                      \
    {                                                                   \
        float v = __half2float(__ushort_as_half((unsigned short)((K) >> 17))); \
        a0 += v * bf2f((unsigned short)(HV)[0]);                        \
        a1 += v * bf2f((unsigned short)(HV)[1]);                        \
        a2 += v * bf2f((unsigned short)(HV)[2]);                        \
        a3 += v * bf2f((unsigned short)(HV)[3]);                        \
        a4 += v * bf2f((unsigned short)(HV)[4]);                        \
        a5 += v * bf2f((unsigned short)(HV)[5]);                        \
        a6 += v * bf2f((unsigned short)(HV)[6]);                        \
        a7 += v * bf2f((unsigned short)(HV)[7]);                        \
    }

    int i = s;
    for (; i + 7 < e; i += 8) {
        unsigned k0 = csr[i + h];
        unsigned k1 = csr[i + 2 + h];
        unsigned k2 = csr[i + 4 + h];
        unsigned k3 = csr[i + 6 + h];
        s16x8 g0 = *(const s16x8*)&H[(k0 & 0x1FFFFu) * 256 + cbase];
        s16x8 g1 = *(const s16x8*)&H[(k1 & 0x1FFFFu) * 256 + cbase];
        s16x8 g2 = *(const s16x8*)&H[(k2 & 0x1FFFFu) * 256 + cbase];
        s16x8 g3 = *(const s16x8*)&H[(k3 & 0x1FFFFu) * 256 + cbase];
        ACC(k0, g0); ACC(k1, g1); ACC(k2, g2); ACC(k3, g3);
    }
    for (; i + 1 < e; i += 2) {
        unsigned k0 = csr[i + h];
        s16x8 g0 = *(const s16x8*)&H[(k0 & 0x1FFFFu) * 256 + cbase];
        ACC(k0, g0);
    }
    if (i < e) {
        // odd tail: both halves gather same row; hi half contributes 0
        unsigned k0 = csr[i];
        s16x8 g0 = *(const s16x8*)&H[(k0 & 0x1FFFFu) * 256 + cbase];
        float v = h ? 0.f
                    : __half2float(__ushort_as_half((unsigned short)(k0 >> 17)));
        a0 += v * bf2f((unsigned short)g0[0]);
        a1 += v * bf2f((unsigned short)g0[1]);
        a2 += v * bf2f((unsigned short)g0[2]);
        a3 += v * bf2f((unsigned short)g0[3]);
        a4 += v * bf2f((unsigned short)g0[4]);
        a5 += v * bf2f((unsigned short)g0[5]);
        a6 += v * bf2f((unsigned short)g0[6]);
        a7 += v * bf2f((unsigned short)g0[7]);
    }
#undef ACC

    a0 += __shfl_xor(a0, 32); a1 += __shfl_xor(a1, 32);
    a2 += __shfl_xor(a2, 32); a3 += __shfl_xor(a3, 32);
    a4 += __shfl_xor(a4, 32); a5 += __shfl_xor(a5, 32);
    a6 += __shfl_xor(a6, 32); a7 += __shfl_xor(a7, 32);

    float w0 = h ? a4 : a0;
    float w1 = h ? a5 : a1;
    float w2 = h ? a6 : a2;
    float w3 = h ? a7 : a3;
    int cw = cbase + h * 4;
    float4 b4 = *(const float4*)&bias[cw];
    float4 o;
    o.x = fmaxf(w0 + b4.x, 0.f);
    o.y = fmaxf(w1 + b4.y, 0.f);
    o.z = fmaxf(w2 + b4.z, 0.f);
    o.w = fmaxf(w3 + b4.w, 0.f);
    *(float4*)&out[(size_t)node * 256 + cw] = o;
}

extern "C" void kernel_launch(void* const* d_in, const int* in_sizes, int n_in,
                              void* d_out, int out_size, void* d_ws, size_t ws_size,
                              hipStream_t stream) {
    const float* x     = (const float*)d_in[0];
    const int*   erow  = (const int*)d_in[1];
    const int*   ecol  = (const int*)d_in[2];
    const float* evals = (const float*)d_in[3];
    const float* W     = (const float*)d_in[4];
    const float* bias  = (const float*)d_in[5];
    float* out = (float*)d_out;

    const int C = 256;
    const int N = in_sizes[0] / C;        // 100000
    const int E = in_sizes[1];            // 3200000
    const int NB = (N + 63) / 64;         // 1563 buckets of 64 rows

    // Workspace carve (256B aligned): 51.2 + 0.13 + 0.01 + 0.8 + 30.4 ~ 82.6MB
    // (ran fine in round 12 -> ws_size >= 82.6MB).
    char* ws = (char*)d_ws;
    size_t off = 0;
    auto carve = [&](size_t bytes) -> void* {
        void* p = ws + off;
        off += (bytes + 255) & ~(size_t)255;
        return p;
    };
    unsigned short* Hbf = (unsigned short*)carve((size_t)N * C * 2);   // 51.2MB
    unsigned short* Wt  = (unsigned short*)carve((size_t)C * 256 * 2); // 0.13MB
    int*            gcur= (int*)carve((size_t)NB * 4);
    int2*           rinf= (int2*)carve((size_t)N * 8);                 // 0.8MB
    int2*           bin8= (int2*)carve((size_t)NB * CAP * 8);          // 30.4MB

    int nA3 = (E + CH_A3 - 1) / CH_A3;    // 391
    int gemmBlocks = (N + 63) / 64;       // 1563

    k_pre<<<257, 256, 0, stream>>>(W, Wt, gcur, NB);
    kD1<<<nA3 + gemmBlocks, 256, D1_SMEM, stream>>>(erow, ecol, evals, gcur,
                                                    bin8, E, NB, nA3,
                                                    x, Wt, Hbf, N);
    kB2<<<NB, 256, 0, stream>>>(bin8, gcur, rinf, N);
    k_agg<<<(N + 3) / 4, 256, 0, stream>>>(Hbf, rinf, (unsigned*)bin8, bias, out, N);
}